// Round 12
// baseline (679.990 us; speedup 1.0000x reference)
//
#include <hip/hip_runtime.h>

#define B_TOT 65536
#define T_STEPS 12
#define LOG2E 1.44269504088896f

typedef short bf16x8 __attribute__((ext_vector_type(8)));
typedef float f32x4 __attribute__((ext_vector_type(4)));

__device__ __forceinline__ unsigned short f2b(float f) {
  unsigned u = __float_as_uint(f);
  u += 0x7fffu + ((u >> 16) & 1u);
  return (unsigned short)(u >> 16);
}
__device__ __forceinline__ float b2f(unsigned short s) {
  return __uint_as_float(((unsigned)s) << 16);
}
__device__ __forceinline__ float fexp2(float x) { return __builtin_amdgcn_exp2f(x); }
__device__ __forceinline__ float frcp(float x) { return __builtin_amdgcn_rcpf(x); }
__device__ __forceinline__ f32x4 mfma16(bf16x8 a, bf16x8 b, f32x4 c) {
  return __builtin_amdgcn_mfma_f32_16x16x32_bf16(a, b, c, 0, 0, 0);
}
__device__ __forceinline__ bf16x8 ld8(const unsigned short* p) {
  return *reinterpret_cast<const bf16x8*>(p);
}

// ---------------------------------------------------------------------------
// Repack W_hh (384x128), W_attn (128x256), [W_mu;W_std] (pad to 16x128) into
// MFMA B-fragment order (bf16) in workspace. Footprint: 167,936 B (proven).
//   B-frag tile (nt,kc): lane l holds W[nt*16+(l&15)][kc*32+(l>>4)*8+e]
// ws layout (u16 elements):
//   [0,     49152)  fragWhh  [24][4][64][8]
//   [49152, 81920)  fragWat  [8][8][64][8]
//   [81920, 83968)  fragWms  [4][64][8]
// ---------------------------------------------------------------------------
__global__ void repack_weights(const float* __restrict__ Whh, const float* __restrict__ Wat,
                               const float* __restrict__ Wmu, const float* __restrict__ Wst,
                               unsigned short* __restrict__ ws) {
  int idx = blockIdx.x * 256 + threadIdx.x;
  if (idx < 49152) {
    int e = idx & 7, ln = (idx >> 3) & 63, kc = (idx >> 9) & 3, nt = idx >> 11;
    int rr = nt * 16 + (ln & 15), kk = kc * 32 + (ln >> 4) * 8 + e;
    ws[idx] = f2b(Whh[rr * 128 + kk]);
  } else if (idx < 81920) {
    int j = idx - 49152;
    int e = j & 7, ln = (j >> 3) & 63, kc = (j >> 9) & 7, nt = j >> 12;
    int rr = nt * 16 + (ln & 15), kk = kc * 32 + (ln >> 4) * 8 + e;
    ws[idx] = f2b(Wat[rr * 256 + kk]);
  } else if (idx < 83968) {
    int j = idx - 81920;
    int e = j & 7, ln = (j >> 3) & 63, kc = j >> 9;
    int rr = ln & 15, kk = kc * 32 + (ln >> 4) * 8 + e;
    float v = (rr < 2) ? Wmu[rr * 128 + kk] : ((rr < 4) ? Wst[(rr - 2) * 128 + kk] : 0.f);
    ws[idx] = f2b(v);
  }
}

// ---------------------------------------------------------------------------
// R12 = R11 (passing, 485us) + two audited micro-changes:
//  (1) s_hf (the only 4-way bank-conflicted LDS structure) removed; f32 h
//      carried in hregA/hregB (8 VGPRs). Producer (Phase C / init) and
//      consumer (Phase A) share the identical (m,rg,r4,colR) mapping on the
//      same thread (concept validated by R10). -16 LDS ops/thread/step.
//  (2) Phase A's 4 scalar hvT stores packed into one uint2 (ds_write_b64);
//      rows rg*4+r4 are contiguous in hvT's inner dim; 8B-aligned.
// No layout, sync, or occupancy changes otherwise.
// ---------------------------------------------------------------------------
__global__ __launch_bounds__(512, 4) void dec_main(
    const float* __restrict__ last_state, const float* __restrict__ enc,
    const float* __restrict__ zin, const float* __restrict__ fut,
    const float* __restrict__ Wdec, const float* __restrict__ bdec,
    const float* __restrict__ Wvel, const float* __restrict__ bvel,
    const float* __restrict__ Wih, const float* __restrict__ bih,
    const float* __restrict__ bhh, const float* __restrict__ batn,
    const float* __restrict__ bmu, const float* __restrict__ bstd,
    const unsigned short* __restrict__ fragW, float* __restrict__ out) {
  constexpr int HP = 136;   // s_h     [32][HP]
  constexpr int GXP = 388;  // s_gxzx  [32][GXP]
  constexpr int ZXP = 296;  // staged zx [32][ZXP] (in pool)
  constexpr int HCP = 264;  // s_hcat  [32][HCP]  (cols 0:128 hv, 128:256 ctx)
  constexpr int TVP = 24;   // s_hvT   [2][128][TVP]

  __shared__ __align__(16) unsigned short s_gxzx[32 * GXP];
  __shared__ __align__(16) unsigned short s_h[32 * HP];
  __shared__ __align__(16) unsigned short s_pool[14592];  // init: zx; steps: hcat(8448)+hvT(6144)
  __shared__ __align__(16) unsigned short s_attn[2 * 16 * 16];
  __shared__ __align__(16) float s_a[32 * 2];

  const int tid = threadIdx.x;
  const int lane = tid & 63;
  const int wv = tid >> 6;   // 0..7
  const int c = lane & 15;   // MFMA col / A-row lane index
  const int rg = lane >> 4;  // 0..3
  const int row0 = blockIdx.x * 32;

  // weight fragment tables in L2-resident workspace (read at use sites)
  const bf16x8* fWhh = (const bf16x8*)(fragW);
  const bf16x8* fWat = (const bf16x8*)(fragW + 49152);
  const bf16x8* fWms = (const bf16x8*)(fragW + 81920);

  const int colR = wv * 16 + c;  // 0..127
  const float wr0 = Wih[(colR)*290 + 288], wr1 = Wih[(colR)*290 + 289];
  const float wz0 = Wih[(colR + 128) * 290 + 288], wz1 = Wih[(colR + 128) * 290 + 289];
  const float wn0 = Wih[(colR + 256) * 290 + 288], wn1 = Wih[(colR + 256) * 290 + 289];
  const float bhr = bhh[colR], bhz = bhh[colR + 128], bhn = bhh[colR + 256];
  const float ba = batn[colR];

  // ---- stage zx = [enc | z] as bf16 into pool ----
#pragma unroll
  for (int i = 0; i < 4; ++i) {
    int f4 = tid + i * 512;  // 2048 float4 over 32x256
    int r = f4 >> 6, cc = (f4 & 63) << 2;
    const float4 v = *(const float4*)(enc + (size_t)(row0 + r) * 256 + cc);
    unsigned short* d = &s_pool[r * ZXP + cc];
    d[0] = f2b(v.x); d[1] = f2b(v.y); d[2] = f2b(v.z); d[3] = f2b(v.w);
  }
  if (tid < 256) {
    int r = tid >> 3, cc = (tid & 7) << 2;  // 256 float4 over 32x32
    const float4 v = *(const float4*)(zin + (size_t)(row0 + r) * 32 + cc);
    unsigned short* d = &s_pool[r * ZXP + 256 + cc];
    d[0] = f2b(v.x); d[1] = f2b(v.y); d[2] = f2b(v.z); d[3] = f2b(v.w);
  }
  // ---- a0 = last_state @ Wvel^T + bvel ----
  if (tid < 64) {
    int r = tid >> 1, j = tid & 1;
    float s = bvel[j];
#pragma unroll
    for (int k = 0; k < 6; ++k) s += last_state[(size_t)(row0 + r) * 6 + k] * Wvel[j * 6 + k];
    s_a[r * 2 + j] = s;
  }
  __syncthreads();

  // ---- init GEMM: gx_zx = zx@Wih[:, :288]^T + bih ; h0 = zx@Wdec^T + bdec ----
  f32x4 hregA, hregB;  // f32 h carry (per m), replaces s_hf
#pragma unroll 1
  for (int i = 0; i < 4; ++i) {
    const int nt = wv + 8 * i;  // 0..23: gx tiles; 24..31 (i==3): h0 tiles
    const bool isH = (i == 3);
    const int nrow = isH ? colR : (nt * 16 + c);
    const float* wp = isH ? (Wdec + (size_t)nrow * 288) : (Wih + (size_t)nrow * 290);
    f32x4 acc[2] = {{0.f, 0.f, 0.f, 0.f}, {0.f, 0.f, 0.f, 0.f}};
#pragma unroll 1
    for (int kc = 0; kc < 9; ++kc) {
      const float* bp = wp + kc * 32 + rg * 8;
      bf16x8 Bf;
#pragma unroll
      for (int e = 0; e < 8; ++e) Bf[e] = (short)f2b(bp[e]);
#pragma unroll
      for (int m = 0; m < 2; ++m) {
        bf16x8 A = ld8(&s_pool[(m * 16 + c) * ZXP + kc * 32 + rg * 8]);
        acc[m] = mfma16(A, Bf, acc[m]);
      }
    }
    if (isH) {
      const float bias = bdec[colR];
#pragma unroll
      for (int m = 0; m < 2; ++m) {
        f32x4 hv;
#pragma unroll
        for (int r4 = 0; r4 < 4; ++r4) {
          int row = m * 16 + rg * 4 + r4;
          float v = acc[m][r4] + bias;
          hv[r4] = v;
          s_h[row * HP + colR] = f2b(v);
        }
        if (m == 0) hregA = hv; else hregB = hv;
      }
    } else {
      const float bias = bih[nt * 16 + c];
#pragma unroll
      for (int m = 0; m < 2; ++m)
#pragma unroll
        for (int r4 = 0; r4 < 4; ++r4) {
          int row = m * 16 + rg * 4 + r4;
          s_gxzx[row * GXP + nt * 16 + c] = f2b(acc[m][r4] + bias);
        }
    }
  }
  __syncthreads();

  unsigned short* s_hcat = s_pool;        // [32][HCP]
  unsigned short* s_hvT = s_pool + 8448;  // [2][128][TVP]
  const int sq = wv >> 2;                 // sequence for attention phases (0..1)
  const int q4 = wv & 3;                  // quarter within sequence

#pragma unroll 1
  for (int t = 0; t < T_STEPS; ++t) {
    // ===== Phase A: gh GEMM + GRU gates -> hv =====
#pragma unroll 1
    for (int m = 0; m < 2; ++m) {
      f32x4 aR = {0.f, 0.f, 0.f, 0.f}, aZ = {0.f, 0.f, 0.f, 0.f}, aN = {0.f, 0.f, 0.f, 0.f};
#pragma unroll
      for (int kc = 0; kc < 4; ++kc) {
        bf16x8 A = ld8(&s_h[(m * 16 + c) * HP + kc * 32 + rg * 8]);
        aR = mfma16(A, fWhh[((wv)*4 + kc) * 64 + lane], aR);
        aZ = mfma16(A, fWhh[((wv + 8) * 4 + kc) * 64 + lane], aZ);
        aN = mfma16(A, fWhh[((wv + 16) * 4 + kc) * 64 + lane], aN);
      }
      const float4 aLo = *(const float4*)&s_a[(m * 16 + rg * 4) * 2];
      const float4 aHi = *(const float4*)&s_a[(m * 16 + rg * 4) * 2 + 4];
      const f32x4 hprev = m ? hregB : hregA;
      f32x4 hv4;
#pragma unroll
      for (int r4 = 0; r4 < 4; ++r4) {
        const int row = m * 16 + rg * 4 + r4;
        const float a0 = (r4 == 0) ? aLo.x : (r4 == 1) ? aLo.z : (r4 == 2) ? aHi.x : aHi.z;
        const float a1 = (r4 == 0) ? aLo.y : (r4 == 1) ? aLo.w : (r4 == 2) ? aHi.y : aHi.w;
        float gr = b2f(s_gxzx[row * GXP + colR]) + a0 * wr0 + a1 * wr1 + bhr + aR[r4];
        float gz = b2f(s_gxzx[row * GXP + 128 + colR]) + a0 * wz0 + a1 * wz1 + bhz + aZ[r4];
        float nx = b2f(s_gxzx[row * GXP + 256 + colR]) + a0 * wn0 + a1 * wn1;
        float nh = bhn + aN[r4];
        float rr = frcp(1.f + fexp2(-LOG2E * gr));
        float zz = frcp(1.f + fexp2(-LOG2E * gz));
        float xx = nx + rr * nh;
        xx = fminf(fmaxf(xx, -15.f), 15.f);
        float e2 = fexp2(2.f * LOG2E * xx);
        float nn = (e2 - 1.f) * frcp(e2 + 1.f);
        float hv = (1.f - zz) * nn + zz * hprev[r4];
        hv4[r4] = hv;
        s_hcat[row * HCP + colR] = f2b(hv);
      }
      // packed hvT write: rows rg*4..rg*4+3 are contiguous in hvT inner dim
      unsigned p01 = (unsigned)f2b(hv4[0]) | ((unsigned)f2b(hv4[1]) << 16);
      unsigned p23 = (unsigned)f2b(hv4[2]) | ((unsigned)f2b(hv4[3]) << 16);
      uint2 pk; pk.x = p01; pk.y = p23;
      *(uint2*)&s_hvT[(m * 128 + colR) * TVP + rg * 4] = pk;
    }
    __syncthreads();

    // ===== Phase B1: score = hv@hv^T (symmetric); softmax split by q4 =====
    {
      f32x4 sc = {0.f, 0.f, 0.f, 0.f};
#pragma unroll
      for (int kc = 0; kc < 4; ++kc) {
        bf16x8 F = ld8(&s_hcat[(sq * 16 + c) * HCP + kc * 32 + rg * 8]);
        sc = mfma16(F, F, sc);
      }
      float v = (q4 == 0) ? sc[0] : (q4 == 1) ? sc[1] : (q4 == 2) ? sc[2] : sc[3];
      float mx = v;
#pragma unroll
      for (int d = 1; d < 16; d <<= 1) mx = fmaxf(mx, __shfl_xor(mx, d));
      float e = fexp2(LOG2E * (v - mx));
      float s = e;
#pragma unroll
      for (int d = 1; d < 16; d <<= 1) s += __shfl_xor(s, d);
      float p = e * frcp(s);
      s_attn[(sq * 16 + rg * 4 + q4) * 16 + c] = f2b(p);
    }
    __syncthreads();

    // ===== Phase B2: ctx = attn @ hv ; wave 6 prefetches next-step a =====
    {
      bf16x8 Aat = {0, 0, 0, 0, 0, 0, 0, 0};
      if (lane < 32) Aat = ld8(&s_attn[(sq * 16 + c) * 16 + rg * 8]);
#pragma unroll
      for (int i = 0; i < 2; ++i) {
        const int dt = q4 * 2 + i;
        bf16x8 Bv = {0, 0, 0, 0, 0, 0, 0, 0};
        if (lane < 32) Bv = ld8(&s_hvT[(sq * 128 + dt * 16 + c) * TVP + rg * 8]);
        f32x4 zz4 = {0.f, 0.f, 0.f, 0.f};
        f32x4 cx = mfma16(Aat, Bv, zz4);
#pragma unroll
        for (int r4 = 0; r4 < 4; ++r4)
          s_hcat[(sq * 16 + rg * 4 + r4) * HCP + 128 + dt * 16 + c] = f2b(cx[r4]);
      }
      if (wv == 6 && t + 1 < T_STEPS)
        s_a[lane] = fut[(size_t)t * B_TOT * 2 + (size_t)row0 * 2 + lane];
    }
    __syncthreads();

    // ===== Phase C: h = [hv|ctx] @ Wat^T + batn -> s_h + hreg =====
#pragma unroll 1
    for (int m = 0; m < 2; ++m) {
      f32x4 acc = {0.f, 0.f, 0.f, 0.f};
#pragma unroll
      for (int kc = 0; kc < 8; ++kc) {
        bf16x8 A = ld8(&s_hcat[(m * 16 + c) * HCP + kc * 32 + rg * 8]);
        acc = mfma16(A, fWat[(wv * 8 + kc) * 64 + lane], acc);
      }
      f32x4 hnew;
#pragma unroll
      for (int r4 = 0; r4 < 4; ++r4) {
        const int row = m * 16 + rg * 4 + r4;
        float v = acc[r4] + ba;
        hnew[r4] = v;
        s_h[row * HP + colR] = f2b(v);
      }
      if (m) hregB = hnew; else hregA = hnew;
    }
    __syncthreads();

    // ===== Phase D (waves 0-1): mu/std -> out. No trailing barrier: D only
    // reads s_h; next-A writes only hcat/hvT (disjoint); s_a write was in B2.
    if (wv < 2) {
      f32x4 acc = {0.f, 0.f, 0.f, 0.f};
#pragma unroll
      for (int kc = 0; kc < 4; ++kc) {
        bf16x8 A = ld8(&s_h[(wv * 16 + c) * HP + kc * 32 + rg * 8]);
        acc = mfma16(A, fWms[kc * 64 + lane], acc);
      }
      if (c < 4) {
#pragma unroll
        for (int r4 = 0; r4 < 4; ++r4) {
          const int gb = row0 + wv * 16 + rg * 4 + r4;
          if (c < 2) {
            out[(size_t)t * B_TOT * 2 + (size_t)gb * 2 + c] = acc[r4] + bmu[c];
          } else {
            float lv = acc[r4] + bstd[c - 2];
            out[(size_t)T_STEPS * B_TOT * 2 + (size_t)t * B_TOT * 2 + (size_t)gb * 2 + (c - 2)] =
                fexp2(0.72134752044448f * lv);
          }
        }
      }
    }
  }
}

extern "C" void kernel_launch(void* const* d_in, const int* in_sizes, int n_in,
                              void* d_out, int out_size, void* d_ws, size_t ws_size,
                              hipStream_t stream) {
  const float* last_state = (const float*)d_in[0];
  const float* enc = (const float*)d_in[1];
  const float* zin = (const float*)d_in[2];
  // d_in[3] seq_start_end: uniform arange(S)*P, unused; d_in[4] fut_obst: unused
  const float* fut = (const float*)d_in[5];
  const float* Wdec = (const float*)d_in[6];
  const float* bdec = (const float*)d_in[7];
  const float* Wvel = (const float*)d_in[8];
  const float* bvel = (const float*)d_in[9];
  const float* Wih = (const float*)d_in[10];
  const float* bih = (const float*)d_in[11];
  const float* Whh = (const float*)d_in[12];
  const float* bhh = (const float*)d_in[13];
  const float* Wat = (const float*)d_in[14];
  const float* batn = (const float*)d_in[15];
  const float* Wmu = (const float*)d_in[16];
  const float* bmu = (const float*)d_in[17];
  const float* Wst = (const float*)d_in[18];
  const float* bstd = (const float*)d_in[19];

  unsigned short* ws = (unsigned short*)d_ws;
  repack_weights<<<328, 256, 0, stream>>>(Whh, Wat, Wmu, Wst, ws);
  dec_main<<<B_TOT / 32, 512, 0, stream>>>(last_state, enc, zin, fut, Wdec, bdec, Wvel, bvel,
                                           Wih, bih, bhh, batn, bmu, bstd, ws, (float*)d_out);
}

// Round 13
// 471.919 us; speedup vs baseline: 1.4409x; 1.4409x over previous
//
#include <hip/hip_runtime.h>

#define B_TOT 65536
#define T_STEPS 12
#define LOG2E 1.44269504088896f

typedef short bf16x8 __attribute__((ext_vector_type(8)));
typedef float f32x4 __attribute__((ext_vector_type(4)));

__device__ __forceinline__ unsigned short f2b(float f) {
  unsigned u = __float_as_uint(f);
  u += 0x7fffu + ((u >> 16) & 1u);
  return (unsigned short)(u >> 16);
}
__device__ __forceinline__ float b2f(unsigned short s) {
  return __uint_as_float(((unsigned)s) << 16);
}
__device__ __forceinline__ float fexp2(float x) { return __builtin_amdgcn_exp2f(x); }
__device__ __forceinline__ float frcp(float x) { return __builtin_amdgcn_rcpf(x); }
__device__ __forceinline__ f32x4 mfma16(bf16x8 a, bf16x8 b, f32x4 c) {
  return __builtin_amdgcn_mfma_f32_16x16x32_bf16(a, b, c, 0, 0, 0);
}
__device__ __forceinline__ bf16x8 ld8(const unsigned short* p) {
  return *reinterpret_cast<const bf16x8*>(p);
}

// ---------------------------------------------------------------------------
// Repack weights into MFMA B-fragment order (bf16) in workspace.
//   B-frag tile (nt,kc): lane l holds W[nt*16+(l&15)][kc*32+(l>>4)*8+e]
// ws layout (u16 elements) — footprint unchanged vs proven 167,936 B:
//   [0,     49152)  fragWhh   [24][4][64][8]   (W_hh 384x128)
//   [49152, 81920)  fragWat   [8][8][64][8]    (W_attn 128x256)
//   [81920, 82944)  fragWcomb [8 kc][4 row][4 rg][8 e]  compact: only the 4
//                   real rows of Wcomb = [Wmu;Wstd]@Wat (4x256); rows 4..15
//                   of the MFMA fragment are zeros constructed at load.
//   [82944, 82952)  bcomb     4 x f32 = [Wmu;Wstd]@batn + [bmu;bstd]
// ---------------------------------------------------------------------------
__global__ void repack_weights(const float* __restrict__ Whh, const float* __restrict__ Wat,
                               const float* __restrict__ Wmu, const float* __restrict__ Wst,
                               const float* __restrict__ batn, const float* __restrict__ bmu,
                               const float* __restrict__ bstd, unsigned short* __restrict__ ws) {
  int idx = blockIdx.x * 256 + threadIdx.x;
  if (idx < 49152) {
    int e = idx & 7, ln = (idx >> 3) & 63, kc = (idx >> 9) & 3, nt = idx >> 11;
    int rr = nt * 16 + (ln & 15), kk = kc * 32 + (ln >> 4) * 8 + e;
    ws[idx] = f2b(Whh[rr * 128 + kk]);
  } else if (idx < 81920) {
    int j = idx - 49152;
    int e = j & 7, ln = (j >> 3) & 63, kc = (j >> 9) & 7, nt = j >> 12;
    int rr = nt * 16 + (ln & 15), kk = kc * 32 + (ln >> 4) * 8 + e;
    ws[idx] = f2b(Wat[rr * 256 + kk]);
  } else if (idx < 82944) {
    int j = idx - 81920;  // [kc][cj][rg][e]
    int e = j & 7, rg = (j >> 3) & 3, cj = (j >> 5) & 3, kc = j >> 7;
    int k = kc * 32 + rg * 8 + e;
    const float* wrow = (cj < 2) ? (Wmu + cj * 128) : (Wst + (cj - 2) * 128);
    float s = 0.f;
    for (int d = 0; d < 128; ++d) s += wrow[d] * Wat[d * 256 + k];
    ws[idx] = f2b(s);
  } else if (idx < 82948) {
    int cj = idx - 82944;
    const float* wrow = (cj < 2) ? (Wmu + cj * 128) : (Wst + (cj - 2) * 128);
    float s = (cj < 2) ? bmu[cj] : bstd[cj - 2];
    for (int d = 0; d < 128; ++d) s += wrow[d] * batn[d];
    ((float*)(ws + 82944))[cj] = s;
  }
}

// ---------------------------------------------------------------------------
// R13 = R11 (passing, 485us) + three changes adding NO long-lived registers
// (R12's hreg carry reverted — 4th confirmed spill mechanism):
//  (1) Phase D fused into Phase C via Wcomb=[Wmu;Wstd]@Wat: outputs computed
//      from s_hcat (stable all of Phase C) by waves 0 (m=0) and 4 (m=1),
//      reusing their existing A-fragments; serial D tail deleted.
//  (2) Phase A's 4 scalar hvT stores -> one uint2 (8B-aligned, contiguous).
//  (3) HFP 129->130: s_hf bank conflict 4-way -> 2-way (free). LDS 80,640 B.
// ---------------------------------------------------------------------------
__global__ __launch_bounds__(512, 4) void dec_main(
    const float* __restrict__ last_state, const float* __restrict__ enc,
    const float* __restrict__ zin, const float* __restrict__ fut,
    const float* __restrict__ Wdec, const float* __restrict__ bdec,
    const float* __restrict__ Wvel, const float* __restrict__ bvel,
    const float* __restrict__ Wih, const float* __restrict__ bih,
    const float* __restrict__ bhh, const float* __restrict__ batn,
    const unsigned short* __restrict__ fragW, float* __restrict__ out) {
  constexpr int HP = 136;   // s_h     [32][HP]
  constexpr int GXP = 388;  // s_gxzx  [32][GXP]
  constexpr int ZXP = 296;  // staged zx [32][ZXP] (in pool)
  constexpr int HCP = 264;  // s_hcat  [32][HCP]  (cols 0:128 hv, 128:256 ctx)
  constexpr int TVP = 24;   // s_hvT   [2][128][TVP]
  constexpr int HFP = 130;  // s_hf    [32][HFP] f32 carry (130: 2-way banks)

  __shared__ __align__(16) unsigned short s_gxzx[32 * GXP];
  __shared__ __align__(16) unsigned short s_h[32 * HP];
  __shared__ __align__(16) float s_hf[32 * HFP];
  __shared__ __align__(16) unsigned short s_pool[14592];  // init: zx; steps: hcat(8448)+hvT(6144)
  __shared__ __align__(16) unsigned short s_attn[2 * 16 * 16];
  __shared__ __align__(16) float s_a[32 * 2];

  const int tid = threadIdx.x;
  const int lane = tid & 63;
  const int wv = tid >> 6;   // 0..7
  const int c = lane & 15;   // MFMA col / A-row lane index
  const int rg = lane >> 4;  // 0..3
  const int row0 = blockIdx.x * 32;

  // weight fragment tables in L2-resident workspace (read at use sites)
  const bf16x8* fWhh = (const bf16x8*)(fragW);
  const bf16x8* fWat = (const bf16x8*)(fragW + 49152);
  const unsigned short* fWcb = fragW + 81920;
  const float* bcb = (const float*)(fragW + 82944);

  const int colR = wv * 16 + c;  // 0..127
  const float wr0 = Wih[(colR)*290 + 288], wr1 = Wih[(colR)*290 + 289];
  const float wz0 = Wih[(colR + 128) * 290 + 288], wz1 = Wih[(colR + 128) * 290 + 289];
  const float wn0 = Wih[(colR + 256) * 290 + 288], wn1 = Wih[(colR + 256) * 290 + 289];
  const float bhr = bhh[colR], bhz = bhh[colR + 128], bhn = bhh[colR + 256];
  const float ba = batn[colR];

  // ---- stage zx = [enc | z] as bf16 into pool ----
#pragma unroll
  for (int i = 0; i < 4; ++i) {
    int f4 = tid + i * 512;  // 2048 float4 over 32x256
    int r = f4 >> 6, cc = (f4 & 63) << 2;
    const float4 v = *(const float4*)(enc + (size_t)(row0 + r) * 256 + cc);
    unsigned short* d = &s_pool[r * ZXP + cc];
    d[0] = f2b(v.x); d[1] = f2b(v.y); d[2] = f2b(v.z); d[3] = f2b(v.w);
  }
  if (tid < 256) {
    int r = tid >> 3, cc = (tid & 7) << 2;  // 256 float4 over 32x32
    const float4 v = *(const float4*)(zin + (size_t)(row0 + r) * 32 + cc);
    unsigned short* d = &s_pool[r * ZXP + 256 + cc];
    d[0] = f2b(v.x); d[1] = f2b(v.y); d[2] = f2b(v.z); d[3] = f2b(v.w);
  }
  // ---- a0 = last_state @ Wvel^T + bvel ----
  if (tid < 64) {
    int r = tid >> 1, j = tid & 1;
    float s = bvel[j];
#pragma unroll
    for (int k = 0; k < 6; ++k) s += last_state[(size_t)(row0 + r) * 6 + k] * Wvel[j * 6 + k];
    s_a[r * 2 + j] = s;
  }
  __syncthreads();

  // ---- init GEMM: gx_zx = zx@Wih[:, :288]^T + bih ; h0 = zx@Wdec^T + bdec ----
#pragma unroll 1
  for (int i = 0; i < 4; ++i) {
    const int nt = wv + 8 * i;  // 0..23: gx tiles; 24..31 (i==3): h0 tiles
    const bool isH = (i == 3);
    const int nrow = isH ? colR : (nt * 16 + c);
    const float* wp = isH ? (Wdec + (size_t)nrow * 288) : (Wih + (size_t)nrow * 290);
    f32x4 acc[2] = {{0.f, 0.f, 0.f, 0.f}, {0.f, 0.f, 0.f, 0.f}};
#pragma unroll 1
    for (int kc = 0; kc < 9; ++kc) {
      const float* bp = wp + kc * 32 + rg * 8;
      bf16x8 Bf;
#pragma unroll
      for (int e = 0; e < 8; ++e) Bf[e] = (short)f2b(bp[e]);
#pragma unroll
      for (int m = 0; m < 2; ++m) {
        bf16x8 A = ld8(&s_pool[(m * 16 + c) * ZXP + kc * 32 + rg * 8]);
        acc[m] = mfma16(A, Bf, acc[m]);
      }
    }
    if (isH) {
      const float bias = bdec[colR];
#pragma unroll
      for (int m = 0; m < 2; ++m)
#pragma unroll
        for (int r4 = 0; r4 < 4; ++r4) {
          int row = m * 16 + rg * 4 + r4;
          float v = acc[m][r4] + bias;
          s_h[row * HP + colR] = f2b(v);
          s_hf[row * HFP + colR] = v;
        }
    } else {
      const float bias = bih[nt * 16 + c];
#pragma unroll
      for (int m = 0; m < 2; ++m)
#pragma unroll
        for (int r4 = 0; r4 < 4; ++r4) {
          int row = m * 16 + rg * 4 + r4;
          s_gxzx[row * GXP + nt * 16 + c] = f2b(acc[m][r4] + bias);
        }
    }
  }
  __syncthreads();

  unsigned short* s_hcat = s_pool;        // [32][HCP]
  unsigned short* s_hvT = s_pool + 8448;  // [2][128][TVP]
  const int sq = wv >> 2;                 // sequence for attention phases (0..1)
  const int q4 = wv & 3;                  // quarter within sequence

#pragma unroll 1
  for (int t = 0; t < T_STEPS; ++t) {
    // ===== Phase A: gh GEMM + GRU gates -> hv =====
#pragma unroll 1
    for (int m = 0; m < 2; ++m) {
      f32x4 aR = {0.f, 0.f, 0.f, 0.f}, aZ = {0.f, 0.f, 0.f, 0.f}, aN = {0.f, 0.f, 0.f, 0.f};
#pragma unroll
      for (int kc = 0; kc < 4; ++kc) {
        bf16x8 A = ld8(&s_h[(m * 16 + c) * HP + kc * 32 + rg * 8]);
        aR = mfma16(A, fWhh[((wv)*4 + kc) * 64 + lane], aR);
        aZ = mfma16(A, fWhh[((wv + 8) * 4 + kc) * 64 + lane], aZ);
        aN = mfma16(A, fWhh[((wv + 16) * 4 + kc) * 64 + lane], aN);
      }
      const float4 aLo = *(const float4*)&s_a[(m * 16 + rg * 4) * 2];
      const float4 aHi = *(const float4*)&s_a[(m * 16 + rg * 4) * 2 + 4];
      f32x4 hv4;
#pragma unroll
      for (int r4 = 0; r4 < 4; ++r4) {
        const int row = m * 16 + rg * 4 + r4;
        const float a0 = (r4 == 0) ? aLo.x : (r4 == 1) ? aLo.z : (r4 == 2) ? aHi.x : aHi.z;
        const float a1 = (r4 == 0) ? aLo.y : (r4 == 1) ? aLo.w : (r4 == 2) ? aHi.y : aHi.w;
        float gr = b2f(s_gxzx[row * GXP + colR]) + a0 * wr0 + a1 * wr1 + bhr + aR[r4];
        float gz = b2f(s_gxzx[row * GXP + 128 + colR]) + a0 * wz0 + a1 * wz1 + bhz + aZ[r4];
        float nx = b2f(s_gxzx[row * GXP + 256 + colR]) + a0 * wn0 + a1 * wn1;
        float nh = bhn + aN[r4];
        float rr = frcp(1.f + fexp2(-LOG2E * gr));
        float zz = frcp(1.f + fexp2(-LOG2E * gz));
        float xx = nx + rr * nh;
        xx = fminf(fmaxf(xx, -15.f), 15.f);
        float e2 = fexp2(2.f * LOG2E * xx);
        float nn = (e2 - 1.f) * frcp(e2 + 1.f);
        float hv = (1.f - zz) * nn + zz * s_hf[row * HFP + colR];
        hv4[r4] = hv;
        s_hcat[row * HCP + colR] = f2b(hv);
      }
      // packed hvT write: rows rg*4..rg*4+3 contiguous in hvT inner dim, 8B-aligned
      unsigned p01 = (unsigned)f2b(hv4[0]) | ((unsigned)f2b(hv4[1]) << 16);
      unsigned p23 = (unsigned)f2b(hv4[2]) | ((unsigned)f2b(hv4[3]) << 16);
      uint2 pk; pk.x = p01; pk.y = p23;
      *(uint2*)&s_hvT[(m * 128 + colR) * TVP + rg * 4] = pk;
    }
    __syncthreads();

    // ===== Phase B1: score = hv@hv^T (symmetric); softmax split by q4 =====
    {
      f32x4 sc = {0.f, 0.f, 0.f, 0.f};
#pragma unroll
      for (int kc = 0; kc < 4; ++kc) {
        bf16x8 F = ld8(&s_hcat[(sq * 16 + c) * HCP + kc * 32 + rg * 8]);
        sc = mfma16(F, F, sc);
      }
      float v = (q4 == 0) ? sc[0] : (q4 == 1) ? sc[1] : (q4 == 2) ? sc[2] : sc[3];
      float mx = v;
#pragma unroll
      for (int d = 1; d < 16; d <<= 1) mx = fmaxf(mx, __shfl_xor(mx, d));
      float e = fexp2(LOG2E * (v - mx));
      float s = e;
#pragma unroll
      for (int d = 1; d < 16; d <<= 1) s += __shfl_xor(s, d);
      float p = e * frcp(s);
      s_attn[(sq * 16 + rg * 4 + q4) * 16 + c] = f2b(p);
    }
    __syncthreads();

    // ===== Phase B2: ctx = attn @ hv ; wave 6 prefetches next-step a =====
    {
      bf16x8 Aat = {0, 0, 0, 0, 0, 0, 0, 0};
      if (lane < 32) Aat = ld8(&s_attn[(sq * 16 + c) * 16 + rg * 8]);
#pragma unroll
      for (int i = 0; i < 2; ++i) {
        const int dt = q4 * 2 + i;
        bf16x8 Bv = {0, 0, 0, 0, 0, 0, 0, 0};
        if (lane < 32) Bv = ld8(&s_hvT[(sq * 128 + dt * 16 + c) * TVP + rg * 8]);
        f32x4 zz4 = {0.f, 0.f, 0.f, 0.f};
        f32x4 cx = mfma16(Aat, Bv, zz4);
#pragma unroll
        for (int r4 = 0; r4 < 4; ++r4)
          s_hcat[(sq * 16 + rg * 4 + r4) * HCP + 128 + dt * 16 + c] = f2b(cx[r4]);
      }
      if (wv == 6 && t + 1 < T_STEPS)
        s_a[lane] = fut[(size_t)t * B_TOT * 2 + (size_t)row0 * 2 + lane];
    }
    __syncthreads();

    // ===== Phase C: h = [hv|ctx] @ Wat^T + batn ; fused mu/std output
    // (waves 0 and 4, from s_hcat via Wcomb — stable all phase) =====
#pragma unroll 1
    for (int m = 0; m < 2; ++m) {
      const bool doOut = (wv == 0 && m == 0) || (wv == 4 && m == 1);
      f32x4 acc = {0.f, 0.f, 0.f, 0.f};
      f32x4 acc2 = {0.f, 0.f, 0.f, 0.f};
#pragma unroll
      for (int kc = 0; kc < 8; ++kc) {
        bf16x8 A = ld8(&s_hcat[(m * 16 + c) * HCP + kc * 32 + rg * 8]);
        acc = mfma16(A, fWat[(wv * 8 + kc) * 64 + lane], acc);
        if (doOut) {
          bf16x8 wf = {0, 0, 0, 0, 0, 0, 0, 0};
          if (c < 4) wf = ld8(&fWcb[((kc * 4 + c) * 4 + rg) * 8]);
          acc2 = mfma16(A, wf, acc2);
        }
      }
#pragma unroll
      for (int r4 = 0; r4 < 4; ++r4) {
        const int row = m * 16 + rg * 4 + r4;
        float v = acc[r4] + ba;
        s_h[row * HP + colR] = f2b(v);
        s_hf[row * HFP + colR] = v;
      }
      if (doOut && c < 4) {
#pragma unroll
        for (int r4 = 0; r4 < 4; ++r4) {
          const int gb = row0 + m * 16 + rg * 4 + r4;
          if (c < 2) {
            out[(size_t)t * B_TOT * 2 + (size_t)gb * 2 + c] = acc2[r4] + bcb[c];
          } else {
            out[(size_t)T_STEPS * B_TOT * 2 + (size_t)t * B_TOT * 2 + (size_t)gb * 2 + (c - 2)] =
                fexp2(0.72134752044448f * (acc2[r4] + bcb[c]));
          }
        }
      }
    }
    __syncthreads();
  }
}

extern "C" void kernel_launch(void* const* d_in, const int* in_sizes, int n_in,
                              void* d_out, int out_size, void* d_ws, size_t ws_size,
                              hipStream_t stream) {
  const float* last_state = (const float*)d_in[0];
  const float* enc = (const float*)d_in[1];
  const float* zin = (const float*)d_in[2];
  // d_in[3] seq_start_end: uniform arange(S)*P, unused; d_in[4] fut_obst: unused
  const float* fut = (const float*)d_in[5];
  const float* Wdec = (const float*)d_in[6];
  const float* bdec = (const float*)d_in[7];
  const float* Wvel = (const float*)d_in[8];
  const float* bvel = (const float*)d_in[9];
  const float* Wih = (const float*)d_in[10];
  const float* bih = (const float*)d_in[11];
  const float* Whh = (const float*)d_in[12];
  const float* bhh = (const float*)d_in[13];
  const float* Wat = (const float*)d_in[14];
  const float* batn = (const float*)d_in[15];
  const float* Wmu = (const float*)d_in[16];
  const float* bmu = (const float*)d_in[17];
  const float* Wst = (const float*)d_in[18];
  const float* bstd = (const float*)d_in[19];

  unsigned short* ws = (unsigned short*)d_ws;
  repack_weights<<<328, 256, 0, stream>>>(Whh, Wat, Wmu, Wst, batn, bmu, bstd, ws);
  dec_main<<<B_TOT / 32, 512, 0, stream>>>(last_state, enc, zin, fut, Wdec, bdec, Wvel, bvel,
                                           Wih, bih, bhh, batn, ws, (float*)d_out);
}